// Round 1
// baseline (71.169 us; speedup 1.0000x reference)
//
#include <hip/hip_runtime.h>

typedef float f32x4 __attribute__((ext_vector_type(4)));
typedef short bf16x8 __attribute__((ext_vector_type(8)));

#define MFMA16(a,b,c) __builtin_amdgcn_mfma_f32_16x16x32_bf16((a),(b),(c),0,0,0)

__device__ __forceinline__ unsigned short f2bf(float f){
  unsigned int u = __builtin_bit_cast(unsigned int, f);
  u += 0x7FFFu + ((u>>16)&1u);
  return (unsigned short)(u>>16);
}

// ---------------- ws layout (bytes) ----------------
#define OFF_SNBF  0u          // 512*384*2      = 393216
#define OFF_PROJ  393216u     // 512*1152*4     = 2359296
#define OFF_QP    2752512u    // 512*144*4      = 294912
#define OFF_KFRAG 3047424u    // 12*32*64*8*2   = 393216
#define OFF_VFRAG 3440640u    // 12*16*3*64*8*2 = 589824
#define OFF_KN2   4030464u    // 12*512*4       = 24576
#define OFF_PLT   4055040u    // 12*512*512*4   = 12582912
#define OFF_OBUF  16637952u   // 512*480*4      = 983040
#define OFF_CATBF 17620992u   // 512*576*2      = 589824
#define OFF_WPBF  18210816u   // 2048*2         = 4096
#define OFF_GZF   18214912u   // 2048*4         = 8192
#define OFF_BZF   18223104u   // 2048*4         = 8192
#define OFF_WCF   18231296u   // 72*12*64*8*2   = 884736
#define OFF_WOF   19116032u   // 24*18*64*8*2   = 442368
#define OFF_WBUF  19558400u   // 12*4 (pad 256)

// ---------------- prep: build bf16 MFMA B-fragments + misc ----------------
__global__ __launch_bounds__(256) void k_prep(
    const float* __restrict__ Wq, const float* __restrict__ Wk, const float* __restrict__ Wv,
    const float* __restrict__ Wqp, const float* __restrict__ Wkp, const float* __restrict__ Wvp,
    const float* __restrict__ Wpb, const float* __restrict__ pw, const float* __restrict__ Wo,
    const float* __restrict__ g_z, const float* __restrict__ b_z,
    unsigned short* __restrict__ wpbfrag, float* __restrict__ gzfrag, float* __restrict__ bzfrag,
    unsigned short* __restrict__ wcfrag, unsigned short* __restrict__ wofrag,
    float* __restrict__ wbuf){
  int idx = blockIdx.x*256 + threadIdx.x;
  const int N_wpb = 2048, N_gz = 2048, N_wc = 72*12*64*8, N_wo = 24*18*64*8;
  if (idx < N_wpb){
    int r = idx&7, lane=(idx>>3)&63, chunk=idx>>9;
    int c = chunk*32 + ((lane>>4)<<3) + r; int h = lane&15;
    wpbfrag[idx] = (h<12) ? f2bf(Wpb[c*12+h]) : (unsigned short)0;
    return;
  }
  idx -= N_wpb;
  if (idx < N_gz){
    int r = idx&7, lane=(idx>>3)&63, chunk=idx>>9;
    int c = chunk*32 + ((lane>>4)<<3) + r;
    gzfrag[idx] = g_z[c]; bzfrag[idx] = b_z[c];
    return;
  }
  idx -= N_gz;
  if (idx < N_wc){
    int r = idx&7, lane=(idx>>3)&63, kt=(idx>>9)%12, nt=idx/(12*512);
    int k = kt*32 + ((lane>>4)<<3) + r; int n = nt*16 + (lane&15);
    float v;
    if      (n < 192) v = Wq [k*192 + n];
    else if (n < 384) v = Wk [k*192 + (n-192)];
    else if (n < 576) v = Wv [k*192 + (n-384)];
    else if (n < 720) v = Wqp[k*144 + (n-576)];
    else if (n < 864) v = Wkp[k*144 + (n-720)];
    else              v = Wvp[k*288 + (n-864)];
    wcfrag[idx] = f2bf(v);
    return;
  }
  idx -= N_wc;
  if (idx < N_wo){
    int r = idx&7, lane=(idx>>3)&63, kt=(idx>>9)%18, nt=idx/(18*512);
    int k = kt*32 + ((lane>>4)<<3) + r; int n = nt*16 + (lane&15);
    wofrag[idx] = f2bf(Wo[k*384 + n]);
    return;
  }
  idx -= N_wo;
  if (idx < 12){
    float x = pw[idx];
    wbuf[idx] = log1pf(expf(x));   // softplus
  }
}

// ---------------- LayerNorm(s) -> bf16 ----------------
__global__ __launch_bounds__(64) void k_lns(const float* __restrict__ s,
    const float* __restrict__ g_s, const float* __restrict__ b_s,
    unsigned short* __restrict__ snbf){
  int l = blockIdx.x; int lane = threadIdx.x;
  float v[6]; float sum=0.f, ss=0.f;
  #pragma unroll
  for (int k=0;k<6;k++){
    float x = s[l*384 + lane + 64*k];
    v[k]=x; sum += x; ss = fmaf(x,x,ss);
  }
  #pragma unroll
  for (int m=1;m<64;m<<=1){ sum += __shfl_xor(sum,m); ss += __shfl_xor(ss,m); }
  float mu = sum*(1.f/384.f);
  float var = ss*(1.f/384.f) - mu*mu;
  float rs = rsqrtf(var + 1e-5f);
  #pragma unroll
  for (int k=0;k<6;k++){
    int c = lane + 64*k;
    snbf[l*384 + c] = f2bf((v[k]-mu)*rs*g_s[c] + b_s[c]);
  }
}

// ---------------- projection GEMM: proj = sn @ Wcat (512x384x1152) ----------------
__global__ __launch_bounds__(256) void k_proj(const unsigned short* __restrict__ snbf,
    const unsigned short* __restrict__ wcfrag, float* __restrict__ proj){
  int wid = blockIdx.x*4 + (threadIdx.x>>6);
  int lane = threadIdx.x & 63;
  int il = lane&15, ig = lane>>4;
  int nt = wid % 72, ib = wid / 72;
  int i0 = ib*16;
  f32x4 acc = {0.f,0.f,0.f,0.f};
  #pragma unroll
  for (int kt=0; kt<12; kt++){
    bf16x8 a = *(const bf16x8*)(snbf + (i0+il)*384 + kt*32 + ig*8);
    bf16x8 b = *(const bf16x8*)(wcfrag + (size_t)((nt*12+kt)*64 + lane)*8);
    acc = MFMA16(a, b, acc);
  }
  #pragma unroll
  for (int r=0;r<4;r++)
    proj[(i0 + ig*4 + r)*1152 + nt*16 + il] = acc[r];
}

// ---------------- rigid transforms + K/V fragment pre-layout ----------------
__global__ __launch_bounds__(192) void k_points(const float* __restrict__ proj,
    const float* __restrict__ Rm, const float* __restrict__ tv,
    float* __restrict__ qpb, unsigned short* __restrict__ kfrag,
    unsigned short* __restrict__ vfrag, float* __restrict__ kn2T){
  int l = blockIdx.x; int t = threadIdx.x;
  __shared__ float Rl[9], tl[3];
  __shared__ float kp_lds[12][12];
  __shared__ float vp_lds[12][24];
  __shared__ float kn2acc[12][4];
  if (t < 9) Rl[t] = Rm[l*9 + t];
  if (t < 3) tl[t] = tv[l*3 + t];
  __syncthreads();
  int h = t >> 4, pt = t & 15;
  {
    int ptype = (pt<4)? 0 : ((pt<8)? 1 : 2);
    int p = pt - ((ptype==0)?0:((ptype==1)?4:8));
    int col0 = (ptype==0)?576:((ptype==1)?720:864);
    int stride = (ptype==2)?24:12;
    const float* src = proj + l*1152 + col0 + h*stride + p*3;
    float lx=src[0], ly=src[1], lz=src[2];
    float cx = Rl[0]*lx + Rl[1]*ly + Rl[2]*lz + tl[0];
    float cy = Rl[3]*lx + Rl[4]*ly + Rl[5]*lz + tl[1];
    float cz = Rl[6]*lx + Rl[7]*ly + Rl[8]*lz + tl[2];
    if (ptype==0){
      float* d = qpb + (l*12 + h)*12 + p*3;
      d[0]=cx; d[1]=cy; d[2]=cz;
    } else if (ptype==1){
      kp_lds[h][p*3+0]=cx; kp_lds[h][p*3+1]=cy; kp_lds[h][p*3+2]=cz;
      kn2acc[h][p] = cx*cx + cy*cy + cz*cz;
    } else {
      vp_lds[h][p*3+0]=cx; vp_lds[h][p*3+1]=cy; vp_lds[h][p*3+2]=cz;
    }
  }
  __syncthreads();
  if (t < 12)
    kn2T[t*512 + l] = kn2acc[t][0]+kn2acc[t][1]+kn2acc[t][2]+kn2acc[t][3];
  // K' fragment: rows j=lane&15, k-label = (lane>>4)*8+r ; K'=[ks(16)|kp(12)|0x4]
  {
    int jt = l >> 4, jl = l & 15;
    int q = pt >> 2, rr = (pt & 3)*2;
    unsigned short* dst = kfrag + (size_t)((h*32 + jt)*64 + 16*q + jl)*8 + rr;
    #pragma unroll
    for (int e=0;e<2;e++){
      int k = pt*2 + e; float f;
      if (k < 16)      f = proj[l*1152 + 192 + h*16 + k];
      else if (k < 28) f = kp_lds[h][k-16];
      else             f = 0.f;
      dst[e] = f2bf(f);
    }
  }
  // V^T fragment: rows d=lane&15, j-label m(q,r)=q*4+(r&3)+16*(r>>2) (matches C-layout of S^T)
  {
    int d = pt; int jc = l >> 5; int jin = l & 31;
    int qq = (jin & 15) >> 2;
    int rr = (jin & 3) + ((jin >> 4) << 2);
    #pragma unroll
    for (int dt=0; dt<3; dt++){
      int dd = dt*16 + d; float f;
      if (dd < 16)      f = proj[l*1152 + 384 + h*16 + dd];
      else if (dd < 40) f = vp_lds[h][dd-16];
      else              f = 0.f;
      vfrag[(size_t)(((h*16 + jc)*3 + dt)*64 + 16*qq + d)*8 + rr] = f2bf(f);
    }
  }
}

// ---------------- fused LN(z) + @Wpb + (-0.5 w kn2[j]) -> plT[h][j][i] ----------------
__global__ __launch_bounds__(256) void k_pairbias(const float* __restrict__ z,
    const unsigned short* __restrict__ wpbfrag, const float* __restrict__ gzfrag,
    const float* __restrict__ bzfrag, const float* __restrict__ kn2T,
    const float* __restrict__ wbuf, float* __restrict__ plT){
  int w = blockIdx.x*4 + (threadIdx.x>>6);
  int lane = threadIdx.x & 63;
  int il = lane & 15, ig = lane >> 4;
  int nw = gridDim.x*4;
  f32x4 gzv[8], bzv[8];
  bf16x8 wf[4];
  #pragma unroll
  for (int c=0;c<4;c++){
    gzv[2*c]   = *(const f32x4*)(gzfrag + (c*64+lane)*8);
    gzv[2*c+1] = *(const f32x4*)(gzfrag + (c*64+lane)*8 + 4);
    bzv[2*c]   = *(const f32x4*)(bzfrag + (c*64+lane)*8);
    bzv[2*c+1] = *(const f32x4*)(bzfrag + (c*64+lane)*8 + 4);
    wf[c] = *(const bf16x8*)(wpbfrag + (c*64+lane)*8);
  }
  float wneg = (il<12) ? -0.5f*wbuf[il] : 0.f;
  for (int g = w; g < 16384; g += nw){
    int j = g >> 5; int i0 = (g & 31) << 4;
    const float* zr = z + (size_t)((i0+il)*512 + j)*128;
    f32x4 zv[8];
    #pragma unroll
    for (int c=0;c<4;c++){
      zv[2*c]   = *(const f32x4*)(zr + c*32 + ig*8);
      zv[2*c+1] = *(const f32x4*)(zr + c*32 + ig*8 + 4);
    }
    float sum=0.f, ss=0.f;
    #pragma unroll
    for (int m=0;m<8;m++)
      #pragma unroll
      for (int e=0;e<4;e++){ float x = zv[m][e]; sum += x; ss = fmaf(x,x,ss); }
    sum += __shfl_xor(sum,16); sum += __shfl_xor(sum,32);
    ss  += __shfl_xor(ss,16);  ss  += __shfl_xor(ss,32);
    float mu  = sum*(1.f/128.f);
    float var = ss*(1.f/128.f) - mu*mu;
    float rs  = rsqrtf(var + 1e-5f);
    f32x4 acc = {0.f,0.f,0.f,0.f};
    #pragma unroll
    for (int c=0;c<4;c++){
      bf16x8 zf;
      #pragma unroll
      for (int r=0;r<8;r++){
        float gv = (r<4)? gzv[2*c][r&3] : gzv[2*c+1][r&3];
        float bv = (r<4)? bzv[2*c][r&3] : bzv[2*c+1][r&3];
        float xv = (r<4)? zv[2*c][r&3]  : zv[2*c+1][r&3];
        zf[r] = (short)f2bf((xv-mu)*(rs*gv) + bv);
      }
      acc = MFMA16(zf, wf[c], acc);
    }
    if (il < 12){
      float tadd = wneg * kn2T[il*512 + j];
      f32x4 ov;
      ov[0]=acc[0]+tadd; ov[1]=acc[1]+tadd; ov[2]=acc[2]+tadd; ov[3]=acc[3]+tadd;
      *(f32x4*)(plT + (size_t)(il*512 + j)*512 + i0 + ig*4) = ov;
    }
  }
}

// ---------------- attention: one wave per (h, 16-row block) ----------------
__global__ __launch_bounds__(64) void k_attn(const float* __restrict__ proj,
    const float* __restrict__ qpb, const float* __restrict__ wbuf,
    const unsigned short* __restrict__ kfrag, const float* __restrict__ plT,
    const unsigned short* __restrict__ vfrag, float* __restrict__ obuf){
  int u = blockIdx.x;
  int h = u % 12, ib = u / 12;
  int i0 = ib*16;
  int lane = threadIdx.x;
  int il = lane & 15, ig = lane >> 4;
  float wh = wbuf[h];
  // Q' = [qs*0.25 (16) | qp*w (12) | 0 (4)], cols i = lane&15, k-label ig*8+r
  bf16x8 qfrag;
  #pragma unroll
  for (int r=0;r<8;r++){
    int k = ig*8 + r; float f;
    if (k < 16)      f = proj[(i0+il)*1152 + h*16 + k]*0.25f;
    else if (k < 28) f = qpb[((i0+il)*12 + h)*12 + (k-16)]*wh;
    else             f = 0.f;
    qfrag[r] = (short)f2bf(f);
  }
  // S^T tiles: rows j, cols i ; C0 = pair bias (with kn2 term folded in)
  f32x4 sv[32];
  const unsigned short* kbase = kfrag + (size_t)(h*32)*64*8;
  #pragma unroll
  for (int jt=0;jt<32;jt++){
    bf16x8 kf = *(const bf16x8*)(kbase + (size_t)(jt*64 + lane)*8);
    f32x4 c0;
    #pragma unroll
    for (int r=0;r<4;r++)
      c0[r] = plT[(size_t)(h*512 + jt*16 + ig*4 + r)*512 + i0 + il];
    sv[jt] = MFMA16(kf, qfrag, c0);
  }
  // softmax over j (lane-local 128 values + xor16/32)
  float mx = -3.0e38f;
  #pragma unroll
  for (int jt=0;jt<32;jt++){
    #pragma unroll
    for (int r=0;r<4;r++) mx = fmaxf(mx, sv[jt][r]);
  }
  mx = fmaxf(mx, __shfl_xor(mx,16));
  mx = fmaxf(mx, __shfl_xor(mx,32));
  float sum = 0.f;
  #pragma unroll
  for (int jt=0;jt<32;jt++){
    #pragma unroll
    for (int r=0;r<4;r++){ float p = __expf(sv[jt][r]-mx); sv[jt][r]=p; sum+=p; }
  }
  sum += __shfl_xor(sum,16);
  sum += __shfl_xor(sum,32);
  float rden = 1.f/sum;
  // O^T = V^T @ P^T
  f32x4 o0={0.f,0.f,0.f,0.f}, o1=o0, o2=o0;
  const unsigned short* vbase = vfrag + (size_t)(h*16)*3*64*8;
  #pragma unroll
  for (int jc=0;jc<16;jc++){
    bf16x8 pfrag;
    #pragma unroll
    for (int r=0;r<8;r++) pfrag[r] = (short)f2bf(sv[2*jc + (r>>2)][r&3]);
    bf16x8 v0 = *(const bf16x8*)(vbase + (size_t)((jc*3+0)*64 + lane)*8);
    bf16x8 v1 = *(const bf16x8*)(vbase + (size_t)((jc*3+1)*64 + lane)*8);
    bf16x8 v2 = *(const bf16x8*)(vbase + (size_t)((jc*3+2)*64 + lane)*8);
    o0 = MFMA16(v0, pfrag, o0);
    o1 = MFMA16(v1, pfrag, o1);
    o2 = MFMA16(v2, pfrag, o2);
  }
  float* orow = obuf + (i0+il)*480 + h*40;
  #pragma unroll
  for (int r=0;r<4;r++){
    orow[ig*4 + r]      = o0[r]*rden;
    orow[16 + ig*4 + r] = o1[r]*rden;
    if (ig < 2) orow[32 + ig*4 + r] = o2[r]*rden;
  }
}

// ---------------- epilogue cat: [out_s | R^T(out_pg - t) | norms] -> bf16 ----------------
__global__ __launch_bounds__(192) void k_cat(const float* __restrict__ obuf,
    const float* __restrict__ Rm, const float* __restrict__ tv,
    unsigned short* __restrict__ catbf){
  int l = blockIdx.x; int t = threadIdx.x;
  __shared__ float Rl[9], tl[3];
  if (t < 9) Rl[t] = Rm[l*9 + t];
  if (t < 3) tl[t] = tv[l*3 + t];
  __syncthreads();
  // out_s copy (192 values)
  catbf[l*576 + t] = f2bf(obuf[l*480 + (t>>4)*40 + (t&15)]);
  if (t < 96){
    int hh = t >> 3, p = t & 7;
    float oy0 = obuf[l*480 + hh*40 + 16 + p*3 + 0] - tl[0];
    float oy1 = obuf[l*480 + hh*40 + 16 + p*3 + 1] - tl[1];
    float oy2 = obuf[l*480 + hh*40 + 16 + p*3 + 2] - tl[2];
    float px = Rl[0]*oy0 + Rl[3]*oy1 + Rl[6]*oy2;
    float py = Rl[1]*oy0 + Rl[4]*oy1 + Rl[7]*oy2;
    float pz = Rl[2]*oy0 + Rl[5]*oy1 + Rl[8]*oy2;
    catbf[l*576 + 192 + t*3 + 0] = f2bf(px);
    catbf[l*576 + 192 + t*3 + 1] = f2bf(py);
    catbf[l*576 + 192 + t*3 + 2] = f2bf(pz);
    catbf[l*576 + 480 + t] = f2bf(sqrtf(px*px + py*py + pz*pz + 1e-8f));
  }
}

// ---------------- output GEMM: out = s + cat @ Wo + bo (512x576x384) ----------------
__global__ __launch_bounds__(256) void k_outgemm(const unsigned short* __restrict__ catbf,
    const unsigned short* __restrict__ wofrag, const float* __restrict__ s,
    const float* __restrict__ bo, float* __restrict__ out){
  int wid = blockIdx.x*4 + (threadIdx.x>>6);
  int lane = threadIdx.x & 63;
  int il = lane&15, ig = lane>>4;
  int nt = wid % 24, ib = wid / 24;
  int i0 = ib*16;
  int n = nt*16 + il;
  f32x4 acc = {0.f,0.f,0.f,0.f};
  #pragma unroll
  for (int kt=0; kt<18; kt++){
    bf16x8 a = *(const bf16x8*)(catbf + (i0+il)*576 + kt*32 + ig*8);
    bf16x8 b = *(const bf16x8*)(wofrag + (size_t)((nt*18+kt)*64 + lane)*8);
    acc = MFMA16(a, b, acc);
  }
  float bv = bo[n];
  #pragma unroll
  for (int r=0;r<4;r++){
    int row = i0 + ig*4 + r;
    out[row*384 + n] = s[row*384 + n] + bv + acc[r];
  }
}

extern "C" void kernel_launch(void* const* d_in, const int* in_sizes, int n_in,
                              void* d_out, int out_size, void* d_ws, size_t ws_size,
                              hipStream_t stream) {
  const float* s   = (const float*)d_in[0];
  const float* z   = (const float*)d_in[1];
  const float* R   = (const float*)d_in[2];
  const float* t   = (const float*)d_in[3];
  const float* g_s = (const float*)d_in[4];
  const float* b_s = (const float*)d_in[5];
  const float* g_z = (const float*)d_in[6];
  const float* b_z = (const float*)d_in[7];
  const float* Wq  = (const float*)d_in[8];
  const float* Wk  = (const float*)d_in[9];
  const float* Wv  = (const float*)d_in[10];
  const float* Wqp = (const float*)d_in[11];
  const float* Wkp = (const float*)d_in[12];
  const float* Wvp = (const float*)d_in[13];
  const float* Wpb = (const float*)d_in[14];
  const float* pw  = (const float*)d_in[15];
  const float* Wo  = (const float*)d_in[16];
  const float* bo  = (const float*)d_in[17];
  float* out = (float*)d_out;
  char* ws = (char*)d_ws;

  unsigned short* snbf    = (unsigned short*)(ws + OFF_SNBF);
  float*          proj    = (float*)(ws + OFF_PROJ);
  float*          qpb     = (float*)(ws + OFF_QP);
  unsigned short* kfrag   = (unsigned short*)(ws + OFF_KFRAG);
  unsigned short* vfrag   = (unsigned short*)(ws + OFF_VFRAG);
  float*          kn2T    = (float*)(ws + OFF_KN2);
  float*          plT     = (float*)(ws + OFF_PLT);
  float*          obuf    = (float*)(ws + OFF_OBUF);
  unsigned short* catbf   = (unsigned short*)(ws + OFF_CATBF);
  unsigned short* wpbfrag = (unsigned short*)(ws + OFF_WPBF);
  float*          gzfrag  = (float*)(ws + OFF_GZF);
  float*          bzfrag  = (float*)(ws + OFF_BZF);
  unsigned short* wcfrag  = (unsigned short*)(ws + OFF_WCF);
  unsigned short* wofrag  = (unsigned short*)(ws + OFF_WOF);
  float*          wbuf    = (float*)(ws + OFF_WBUF);

  k_prep<<<2609, 256, 0, stream>>>(Wq, Wk, Wv, Wqp, Wkp, Wvp, Wpb, pw, Wo, g_z, b_z,
                                   wpbfrag, gzfrag, bzfrag, wcfrag, wofrag, wbuf);
  k_lns<<<512, 64, 0, stream>>>(s, g_s, b_s, snbf);
  k_proj<<<576, 256, 0, stream>>>(snbf, wcfrag, proj);
  k_points<<<512, 192, 0, stream>>>(proj, R, t, qpb, kfrag, vfrag, kn2T);
  k_pairbias<<<1024, 256, 0, stream>>>(z, wpbfrag, gzfrag, bzfrag, kn2T, wbuf, plT);
  k_attn<<<384, 64, 0, stream>>>(proj, qpb, wbuf, kfrag, plT, vfrag, obuf);
  k_cat<<<512, 192, 0, stream>>>(obuf, R, t, catbf);
  k_outgemm<<<192, 256, 0, stream>>>(catbf, wofrag, s, bo, out);
}

// Round 2
// 61.038 us; speedup vs baseline: 1.1660x; 1.1660x over previous
//
#include <hip/hip_runtime.h>

typedef float f32x4 __attribute__((ext_vector_type(4)));
typedef short bf16x8 __attribute__((ext_vector_type(8)));
typedef unsigned short u16x4 __attribute__((ext_vector_type(4)));

#define MFMA16(a,b,c) __builtin_amdgcn_mfma_f32_16x16x32_bf16((a),(b),(c),0,0,0)

__device__ __forceinline__ unsigned short f2bf(float f){
  unsigned int u = __builtin_bit_cast(unsigned int, f);
  u += 0x7FFFu + ((u>>16)&1u);
  return (unsigned short)(u>>16);
}
__device__ __forceinline__ float bf2f(unsigned short u){
  return __builtin_bit_cast(float, ((unsigned int)u)<<16);
}

// ---------------- ws layout (bytes) ----------------
#define OFF_SNBF  0u          // 512*384*2      = 393216
#define OFF_PROJ  393216u     // 512*1152*4     = 2359296
#define OFF_QP    2752512u    // 512*144*4      = 294912
#define OFF_KFRAG 3047424u    // 12*32*64*8*2   = 393216
#define OFF_VFRAG 3440640u    // 12*16*3*64*8*2 = 589824
#define OFF_KN2   4030464u    // 12*512*4       = 24576
#define OFF_PLT   4055040u    // 12*512*512*2   = 6291456 (bf16)
#define OFF_OBUF  10346496u   // 512*480*4      = 983040
#define OFF_CATBF 11329536u   // 512*576*2      = 589824
#define OFF_WPBF  11919360u   // 2048*2 (pad)   = 4096
#define OFF_GZF   11923456u   // 2048*4         = 8192
#define OFF_BZF   11931648u   // 2048*4         = 8192
#define OFF_WCF   11939840u   // 72*12*64*8*2   = 884736
#define OFF_WOF   12824576u   // 24*18*64*8*2   = 442368
#define OFF_WBUF  13266944u   // 12*4

// ---------------- merged: LN(s)->bf16  +  weight fragment prep ----------------
__global__ __launch_bounds__(256) void k_prep(
    const float* __restrict__ s, const float* __restrict__ g_s, const float* __restrict__ b_s,
    unsigned short* __restrict__ snbf,
    const float* __restrict__ Wq, const float* __restrict__ Wk, const float* __restrict__ Wv,
    const float* __restrict__ Wqp, const float* __restrict__ Wkp, const float* __restrict__ Wvp,
    const float* __restrict__ Wpb, const float* __restrict__ pw, const float* __restrict__ Wo,
    const float* __restrict__ g_z, const float* __restrict__ b_z,
    unsigned short* __restrict__ wpbfrag, float* __restrict__ gzfrag, float* __restrict__ bzfrag,
    unsigned short* __restrict__ wcfrag, unsigned short* __restrict__ wofrag,
    float* __restrict__ wbuf){
  if (blockIdx.x < 128){
    // LayerNorm(s): 4 rows per block, one wave each
    int l = blockIdx.x*4 + (threadIdx.x>>6);
    int lane = threadIdx.x & 63;
    float v[6]; float sum=0.f, ss=0.f;
    #pragma unroll
    for (int k=0;k<6;k++){
      float x = s[l*384 + lane + 64*k];
      v[k]=x; sum += x; ss = fmaf(x,x,ss);
    }
    #pragma unroll
    for (int m=1;m<64;m<<=1){ sum += __shfl_xor(sum,m); ss += __shfl_xor(ss,m); }
    float mu = sum*(1.f/384.f);
    float var = ss*(1.f/384.f) - mu*mu;
    float rs = rsqrtf(var + 1e-5f);
    #pragma unroll
    for (int k=0;k<6;k++){
      int c = lane + 64*k;
      snbf[l*384 + c] = f2bf((v[k]-mu)*rs*g_s[c] + b_s[c]);
    }
    return;
  }
  int idx = (blockIdx.x-128)*256 + threadIdx.x;
  const int N_wpb = 2048, N_gz = 2048, N_wc = 72*12*64*8, N_wo = 24*18*64*8;
  if (idx < N_wpb){
    int r = idx&7, lane=(idx>>3)&63, chunk=idx>>9;
    int c = chunk*32 + ((lane>>4)<<3) + r; int h = lane&15;
    wpbfrag[idx] = (h<12) ? f2bf(Wpb[c*12+h]) : (unsigned short)0;
    return;
  }
  idx -= N_wpb;
  if (idx < N_gz){
    int r = idx&7, lane=(idx>>3)&63, chunk=idx>>9;
    int c = chunk*32 + ((lane>>4)<<3) + r;
    gzfrag[idx] = g_z[c]; bzfrag[idx] = b_z[c];
    return;
  }
  idx -= N_gz;
  if (idx < N_wc){
    int r = idx&7, lane=(idx>>3)&63, kt=(idx>>9)%12, nt=idx/(12*512);
    int k = kt*32 + ((lane>>4)<<3) + r; int n = nt*16 + (lane&15);
    float v;
    if      (n < 192) v = Wq [k*192 + n];
    else if (n < 384) v = Wk [k*192 + (n-192)];
    else if (n < 576) v = Wv [k*192 + (n-384)];
    else if (n < 720) v = Wqp[k*144 + (n-576)];
    else if (n < 864) v = Wkp[k*144 + (n-720)];
    else              v = Wvp[k*288 + (n-864)];
    wcfrag[idx] = f2bf(v);
    return;
  }
  idx -= N_wc;
  if (idx < N_wo){
    int r = idx&7, lane=(idx>>3)&63, kt=(idx>>9)%18, nt=idx/(18*512);
    int k = kt*32 + ((lane>>4)<<3) + r; int n = nt*16 + (lane&15);
    wofrag[idx] = f2bf(Wo[k*384 + n]);
    return;
  }
  idx -= N_wo;
  if (idx < 12){
    float x = pw[idx];
    wbuf[idx] = log1pf(expf(x));   // softplus
  }
}

// ---------------- projection GEMM: proj = sn @ Wcat (512x384x1152) ----------------
__global__ __launch_bounds__(256) void k_proj(const unsigned short* __restrict__ snbf,
    const unsigned short* __restrict__ wcfrag, float* __restrict__ proj){
  int wid = blockIdx.x*4 + (threadIdx.x>>6);
  int lane = threadIdx.x & 63;
  int il = lane&15, ig = lane>>4;
  int nt = wid % 72, ib = wid / 72;
  int i0 = ib*16;
  f32x4 acc = {0.f,0.f,0.f,0.f};
  #pragma unroll
  for (int kt=0; kt<12; kt++){
    bf16x8 a = *(const bf16x8*)(snbf + (i0+il)*384 + kt*32 + ig*8);
    bf16x8 b = *(const bf16x8*)(wcfrag + (size_t)((nt*12+kt)*64 + lane)*8);
    acc = MFMA16(a, b, acc);
  }
  #pragma unroll
  for (int r=0;r<4;r++)
    proj[(i0 + ig*4 + r)*1152 + nt*16 + il] = acc[r];
}

// ---------------- rigid transforms + K/V fragment pre-layout ----------------
__global__ __launch_bounds__(192) void k_points(const float* __restrict__ proj,
    const float* __restrict__ Rm, const float* __restrict__ tv,
    float* __restrict__ qpb, unsigned short* __restrict__ kfrag,
    unsigned short* __restrict__ vfrag, float* __restrict__ kn2T){
  int l = blockIdx.x; int t = threadIdx.x;
  __shared__ float Rl[9], tl[3];
  __shared__ float kp_lds[12][12];
  __shared__ float vp_lds[12][24];
  __shared__ float kn2acc[12][4];
  if (t < 9) Rl[t] = Rm[l*9 + t];
  if (t < 3) tl[t] = tv[l*3 + t];
  __syncthreads();
  int h = t >> 4, pt = t & 15;
  {
    int ptype = (pt<4)? 0 : ((pt<8)? 1 : 2);
    int p = pt - ((ptype==0)?0:((ptype==1)?4:8));
    int col0 = (ptype==0)?576:((ptype==1)?720:864);
    int stride = (ptype==2)?24:12;
    const float* src = proj + l*1152 + col0 + h*stride + p*3;
    float lx=src[0], ly=src[1], lz=src[2];
    float cx = Rl[0]*lx + Rl[1]*ly + Rl[2]*lz + tl[0];
    float cy = Rl[3]*lx + Rl[4]*ly + Rl[5]*lz + tl[1];
    float cz = Rl[6]*lx + Rl[7]*ly + Rl[8]*lz + tl[2];
    if (ptype==0){
      float* d = qpb + (l*12 + h)*12 + p*3;
      d[0]=cx; d[1]=cy; d[2]=cz;
    } else if (ptype==1){
      kp_lds[h][p*3+0]=cx; kp_lds[h][p*3+1]=cy; kp_lds[h][p*3+2]=cz;
      kn2acc[h][p] = cx*cx + cy*cy + cz*cz;
    } else {
      vp_lds[h][p*3+0]=cx; vp_lds[h][p*3+1]=cy; vp_lds[h][p*3+2]=cz;
    }
  }
  __syncthreads();
  if (t < 12)
    kn2T[t*512 + l] = kn2acc[t][0]+kn2acc[t][1]+kn2acc[t][2]+kn2acc[t][3];
  // K' fragment: rows j=lane&15, k-label = (lane>>4)*8+r ; K'=[ks(16)|kp(12)|0x4]
  {
    int jt = l >> 4, jl = l & 15;
    int q = pt >> 2, rr = (pt & 3)*2;
    unsigned short* dst = kfrag + (size_t)((h*32 + jt)*64 + 16*q + jl)*8 + rr;
    #pragma unroll
    for (int e=0;e<2;e++){
      int k = pt*2 + e; float f;
      if (k < 16)      f = proj[l*1152 + 192 + h*16 + k];
      else if (k < 28) f = kp_lds[h][k-16];
      else             f = 0.f;
      dst[e] = f2bf(f);
    }
  }
  // V^T fragment: rows d=lane&15, j-label m(q,r)=q*4+(r&3)+16*(r>>2)
  {
    int d = pt; int jc = l >> 5; int jin = l & 31;
    int qq = (jin & 15) >> 2;
    int rr = (jin & 3) + ((jin >> 4) << 2);
    #pragma unroll
    for (int dt=0; dt<3; dt++){
      int dd = dt*16 + d; float f;
      if (dd < 16)      f = proj[l*1152 + 384 + h*16 + dd];
      else if (dd < 40) f = vp_lds[h][dd-16];
      else              f = 0.f;
      vfrag[(size_t)(((h*16 + jc)*3 + dt)*64 + 16*qq + d)*8 + rr] = f2bf(f);
    }
  }
}

// ---------------- fused LN(z) + @Wpb -> plTbf[h][j][i] (bf16) ----------------
__global__ __launch_bounds__(256) void k_pairbias(const float* __restrict__ z,
    const unsigned short* __restrict__ wpbfrag, const float* __restrict__ gzfrag,
    const float* __restrict__ bzfrag, unsigned short* __restrict__ plTbf){
  int w = blockIdx.x*4 + (threadIdx.x>>6);
  int lane = threadIdx.x & 63;
  int il = lane & 15, ig = lane >> 4;
  int nw = gridDim.x*4;
  f32x4 gzv[8], bzv[8];
  bf16x8 wf[4];
  #pragma unroll
  for (int c=0;c<4;c++){
    gzv[2*c]   = *(const f32x4*)(gzfrag + (c*64+lane)*8);
    gzv[2*c+1] = *(const f32x4*)(gzfrag + (c*64+lane)*8 + 4);
    bzv[2*c]   = *(const f32x4*)(bzfrag + (c*64+lane)*8);
    bzv[2*c+1] = *(const f32x4*)(bzfrag + (c*64+lane)*8 + 4);
    wf[c] = *(const bf16x8*)(wpbfrag + (c*64+lane)*8);
  }
  for (int g = w; g < 16384; g += nw){
    int j = g >> 5; int i0 = (g & 31) << 4;
    const float* zr = z + (size_t)((i0+il)*512 + j)*128;
    f32x4 zv[8];
    #pragma unroll
    for (int c=0;c<4;c++){
      zv[2*c]   = *(const f32x4*)(zr + c*32 + ig*8);
      zv[2*c+1] = *(const f32x4*)(zr + c*32 + ig*8 + 4);
    }
    float sum=0.f, ss=0.f;
    #pragma unroll
    for (int m=0;m<8;m++)
      #pragma unroll
      for (int e=0;e<4;e++){ float x = zv[m][e]; sum += x; ss = fmaf(x,x,ss); }
    sum += __shfl_xor(sum,16); sum += __shfl_xor(sum,32);
    ss  += __shfl_xor(ss,16);  ss  += __shfl_xor(ss,32);
    float mu  = sum*(1.f/128.f);
    float var = ss*(1.f/128.f) - mu*mu;
    float rs  = rsqrtf(var + 1e-5f);
    f32x4 acc = {0.f,0.f,0.f,0.f};
    #pragma unroll
    for (int c=0;c<4;c++){
      bf16x8 zf;
      #pragma unroll
      for (int r=0;r<8;r++){
        float gv = (r<4)? gzv[2*c][r&3] : gzv[2*c+1][r&3];
        float bv = (r<4)? bzv[2*c][r&3] : bzv[2*c+1][r&3];
        float xv = (r<4)? zv[2*c][r&3]  : zv[2*c+1][r&3];
        zf[r] = (short)f2bf((xv-mu)*(rs*gv) + bv);
      }
      acc = MFMA16(zf, wf[c], acc);
    }
    if (il < 12){
      u16x4 ov;
      #pragma unroll
      for (int r=0;r<4;r++) ov[r] = f2bf(acc[r]);
      *(u16x4*)(plTbf + (size_t)(il*512 + j)*512 + i0 + ig*4) = ov;
    }
  }
}

// ---------------- attention: block per (h, 16-row block), 8 waves split over j ----------------
__global__ __launch_bounds__(512) void k_attn(const float* __restrict__ proj,
    const float* __restrict__ qpb, const float* __restrict__ wbuf,
    const unsigned short* __restrict__ kfrag, const unsigned short* __restrict__ plTbf,
    const float* __restrict__ kn2T, const unsigned short* __restrict__ vfrag,
    float* __restrict__ obuf){
  int u = blockIdx.x;
  int h = u % 12, ib = u / 12;
  int i0 = ib*16;
  int tid = threadIdx.x;
  int w = tid >> 6, lane = tid & 63;
  int il = lane & 15, ig = lane >> 4;
  __shared__ float red[8][16];
  __shared__ float gsum[16];
  __shared__ float osum[8][64][13];
  float wh = wbuf[h];
  float wneg = -0.5f*wh;
  // Q' = [qs*0.25 (16) | qp*w (12) | 0 (4)], cols i = lane&15, k-label ig*8+r
  bf16x8 qfrag;
  #pragma unroll
  for (int r=0;r<8;r++){
    int k = ig*8 + r; float f;
    if (k < 16)      f = proj[(i0+il)*1152 + h*16 + k]*0.25f;
    else if (k < 28) f = qpb[((i0+il)*12 + h)*12 + (k-16)]*wh;
    else             f = 0.f;
    qfrag[r] = (short)f2bf(f);
  }
  // S^T tiles for this wave's j-range (4 jt tiles = 64 j)
  int jt0 = w*4;
  f32x4 sv[4];
  const unsigned short* kbase = kfrag + (size_t)(h*32)*64*8;
  const unsigned short* pbase = plTbf + (size_t)(h*512)*512;
  const float* kbn = kn2T + h*512;
  #pragma unroll
  for (int jj=0;jj<4;jj++){
    int jt = jt0+jj;
    bf16x8 kf = *(const bf16x8*)(kbase + (size_t)(jt*64 + lane)*8);
    f32x4 c0;
    #pragma unroll
    for (int r=0;r<4;r++){
      int j = jt*16 + ig*4 + r;
      c0[r] = bf2f(pbase[(size_t)j*512 + i0 + il]) + wneg*kbn[j];
    }
    sv[jj] = MFMA16(kf, qfrag, c0);
  }
  // wave-local max per column i=il, then cross-wave via LDS
  float mx = -3.0e38f;
  #pragma unroll
  for (int jj=0;jj<4;jj++){
    #pragma unroll
    for (int r=0;r<4;r++) mx = fmaxf(mx, sv[jj][r]);
  }
  mx = fmaxf(mx, __shfl_xor(mx,16));
  mx = fmaxf(mx, __shfl_xor(mx,32));
  if (lane < 16) red[w][lane] = mx;
  __syncthreads();
  float gm = red[0][il];
  #pragma unroll
  for (int ww=1;ww<8;ww++) gm = fmaxf(gm, red[ww][il]);
  __syncthreads();
  // exp + local sum, cross-wave sum
  float sum = 0.f;
  #pragma unroll
  for (int jj=0;jj<4;jj++){
    #pragma unroll
    for (int r=0;r<4;r++){ float p = __expf(sv[jj][r]-gm); sv[jj][r]=p; sum+=p; }
  }
  sum += __shfl_xor(sum,16);
  sum += __shfl_xor(sum,32);
  if (lane < 16) red[w][lane] = sum;
  __syncthreads();
  float gs = 0.f;
  #pragma unroll
  for (int ww=0;ww<8;ww++) gs += red[ww][il];
  if (w == 0 && lane < 16) gsum[lane] = gs;
  // partial O^T = V^T @ P^T over this wave's j-range (2 jc blocks)
  f32x4 o0={0.f,0.f,0.f,0.f}, o1=o0, o2=o0;
  const unsigned short* vbase = vfrag + (size_t)(h*16)*3*64*8;
  #pragma unroll
  for (int jcl=0;jcl<2;jcl++){
    int jc = w*2 + jcl;
    bf16x8 pfrag;
    #pragma unroll
    for (int r=0;r<8;r++) pfrag[r] = (short)f2bf(sv[2*jcl + (r>>2)][r&3]);
    bf16x8 v0 = *(const bf16x8*)(vbase + (size_t)((jc*3+0)*64 + lane)*8);
    bf16x8 v1 = *(const bf16x8*)(vbase + (size_t)((jc*3+1)*64 + lane)*8);
    bf16x8 v2 = *(const bf16x8*)(vbase + (size_t)((jc*3+2)*64 + lane)*8);
    o0 = MFMA16(v0, pfrag, o0);
    o1 = MFMA16(v1, pfrag, o1);
    o2 = MFMA16(v2, pfrag, o2);
  }
  #pragma unroll
  for (int r=0;r<4;r++){
    osum[w][lane][r]   = o0[r];
    osum[w][lane][4+r] = o1[r];
    osum[w][lane][8+r] = o2[r];
  }
  __syncthreads();
  // combine across waves: 640 outputs (40 d x 16 i)
  for (int idx = tid; idx < 640; idx += 512){
    int i = idx & 15, d = idx >> 4;
    int seg = d >> 4, dr = d & 15;
    int lx = ((dr>>2) << 4) + i;
    int c = seg*4 + (dr & 3);
    float v = 0.f;
    #pragma unroll
    for (int ww=0;ww<8;ww++) v += osum[ww][lx][c];
    obuf[(i0+i)*480 + h*40 + d] = v / gsum[i];
  }
}

// ---------------- epilogue cat: [out_s | R^T(out_pg - t) | norms] -> bf16 ----------------
__global__ __launch_bounds__(192) void k_cat(const float* __restrict__ obuf,
    const float* __restrict__ Rm, const float* __restrict__ tv,
    unsigned short* __restrict__ catbf){
  int l = blockIdx.x; int t = threadIdx.x;
  __shared__ float Rl[9], tl[3];
  if (t < 9) Rl[t] = Rm[l*9 + t];
  if (t < 3) tl[t] = tv[l*3 + t];
  __syncthreads();
  catbf[l*576 + t] = f2bf(obuf[l*480 + (t>>4)*40 + (t&15)]);
  if (t < 96){
    int hh = t >> 3, p = t & 7;
    float oy0 = obuf[l*480 + hh*40 + 16 + p*3 + 0] - tl[0];
    float oy1 = obuf[l*480 + hh*40 + 16 + p*3 + 1] - tl[1];
    float oy2 = obuf[l*480 + hh*40 + 16 + p*3 + 2] - tl[2];
    float px = Rl[0]*oy0 + Rl[3]*oy1 + Rl[6]*oy2;
    float py = Rl[1]*oy0 + Rl[4]*oy1 + Rl[7]*oy2;
    float pz = Rl[2]*oy0 + Rl[5]*oy1 + Rl[8]*oy2;
    catbf[l*576 + 192 + t*3 + 0] = f2bf(px);
    catbf[l*576 + 192 + t*3 + 1] = f2bf(py);
    catbf[l*576 + 192 + t*3 + 2] = f2bf(pz);
    catbf[l*576 + 480 + t] = f2bf(sqrtf(px*px + py*py + pz*pz + 1e-8f));
  }
}

// ---------------- output GEMM: out = s + cat @ Wo + bo (512x576x384) ----------------
__global__ __launch_bounds__(256) void k_outgemm(const unsigned short* __restrict__ catbf,
    const unsigned short* __restrict__ wofrag, const float* __restrict__ s,
    const float* __restrict__ bo, float* __restrict__ out){
  int wid = blockIdx.x*4 + (threadIdx.x>>6);
  int lane = threadIdx.x & 63;
  int il = lane&15, ig = lane>>4;
  int nt = wid % 24, ib = wid / 24;
  int i0 = ib*16;
  int n = nt*16 + il;
  f32x4 acc = {0.f,0.f,0.f,0.f};
  #pragma unroll
  for (int kt=0; kt<18; kt++){
    bf16x8 a = *(const bf16x8*)(catbf + (i0+il)*576 + kt*32 + ig*8);
    bf16x8 b = *(const bf16x8*)(wofrag + (size_t)((nt*18+kt)*64 + lane)*8);
    acc = MFMA16(a, b, acc);
  }
  float bv = bo[n];
  #pragma unroll
  for (int r=0;r<4;r++){
    int row = i0 + ig*4 + r;
    out[row*384 + n] = s[row*384 + n] + bv + acc[r];
  }
}

extern "C" void kernel_launch(void* const* d_in, const int* in_sizes, int n_in,
                              void* d_out, int out_size, void* d_ws, size_t ws_size,
                              hipStream_t stream) {
  const float* s   = (const float*)d_in[0];
  const float* z   = (const float*)d_in[1];
  const float* R   = (const float*)d_in[2];
  const float* t   = (const float*)d_in[3];
  const float* g_s = (const float*)d_in[4];
  const float* b_s = (const float*)d_in[5];
  const float* g_z = (const float*)d_in[6];
  const float* b_z = (const float*)d_in[7];
  const float* Wq  = (const float*)d_in[8];
  const float* Wk  = (const float*)d_in[9];
  const float* Wv  = (const float*)d_in[10];
  const float* Wqp = (const float*)d_in[11];
  const float* Wkp = (const float*)d_in[12];
  const float* Wvp = (const float*)d_in[13];
  const float* Wpb = (const float*)d_in[14];
  const float* pw  = (const float*)d_in[15];
  const float* Wo  = (const float*)d_in[16];
  const float* bo  = (const float*)d_in[17];
  float* out = (float*)d_out;
  char* ws = (char*)d_ws;

  unsigned short* snbf    = (unsigned short*)(ws + OFF_SNBF);
  float*          proj    = (float*)(ws + OFF_PROJ);
  float*          qpb     = (float*)(ws + OFF_QP);
  unsigned short* kfrag   = (unsigned short*)(ws + OFF_KFRAG);
  unsigned short* vfrag   = (unsigned short*)(ws + OFF_VFRAG);
  float*          kn2T    = (float*)(ws + OFF_KN2);
  unsigned short* plTbf   = (unsigned short*)(ws + OFF_PLT);
  float*          obuf    = (float*)(ws + OFF_OBUF);
  unsigned short* catbf   = (unsigned short*)(ws + OFF_CATBF);
  unsigned short* wpbfrag = (unsigned short*)(ws + OFF_WPBF);
  float*          gzfrag  = (float*)(ws + OFF_GZF);
  float*          bzfrag  = (float*)(ws + OFF_BZF);
  unsigned short* wcfrag  = (unsigned short*)(ws + OFF_WCF);
  unsigned short* wofrag  = (unsigned short*)(ws + OFF_WOF);
  float*          wbuf    = (float*)(ws + OFF_WBUF);

  k_prep<<<2737, 256, 0, stream>>>(s, g_s, b_s, snbf,
                                   Wq, Wk, Wv, Wqp, Wkp, Wvp, Wpb, pw, Wo, g_z, b_z,
                                   wpbfrag, gzfrag, bzfrag, wcfrag, wofrag, wbuf);
  k_proj<<<576, 256, 0, stream>>>(snbf, wcfrag, proj);
  k_points<<<512, 192, 0, stream>>>(proj, R, t, qpb, kfrag, vfrag, kn2T);
  k_pairbias<<<1024, 256, 0, stream>>>(z, wpbfrag, gzfrag, bzfrag, plTbf);
  k_attn<<<384, 512, 0, stream>>>(proj, qpb, wbuf, kfrag, plTbf, kn2T, vfrag, obuf);
  k_cat<<<512, 192, 0, stream>>>(obuf, R, t, catbf);
  k_outgemm<<<192, 256, 0, stream>>>(catbf, wofrag, s, bo, out);
}